// Round 2
// baseline (1332.203 us; speedup 1.0000x reference)
//
#include <hip/hip_runtime.h>
#include <hip/hip_bf16.h>
#include <math.h>

// N=1, L=1024, DN=1024, DP=64, H=12, C=16
#define LLEN 1024
#define DNN  1024
#define HNUM 12
#define CNUM 16
#define HC   192
#define DPP  64

constexpr float kINF = 100000.0f;
constexpr float kC2  = 0.23570226039551584f;  // sqrt(2/9)/2
constexpr float kS   = 0.57735026918962576f;  // sqrt(1/3)

__device__ __forceinline__ float softplusf(float x) {
  return fmaxf(x, 0.f) + log1pf(expf(-fabsf(x)));
}

__device__ __forceinline__ float warp_red_sum(float v) {
  #pragma unroll
  for (int o = 32; o > 0; o >>= 1) v += __shfl_down(v, o);
  return v;
}

// ---------------- xsum[f] = sum_rows x[r][f] (for Ksum = xsum @ Wk) -------
__global__ __launch_bounds__(256) void k_xsum(const float* __restrict__ x,
                                              float* __restrict__ xsum) {
  int c0 = threadIdx.x;
  int r0 = blockIdx.x * 16;
  float acc[4] = {0.f, 0.f, 0.f, 0.f};
  for (int r = 0; r < 16; ++r) {
    const float* row = x + (size_t)(r0 + r) * DNN;
    #pragma unroll
    for (int kq = 0; kq < 4; ++kq) acc[kq] += row[c0 + kq * 256];
  }
  #pragma unroll
  for (int kq = 0; kq < 4; ++kq) atomicAdd(&xsum[c0 + kq * 256], acc[kq]);
}

// ---------------- wpbsum, lamBase, Gsum ----------------------------------
__global__ void k_misc(const float* __restrict__ Wpb, const float* __restrict__ sc,
                       float* __restrict__ wpbsum, float* __restrict__ lamBase,
                       float* __restrict__ Gsum) {
  int t = threadIdx.x;
  if (t < 64) {
    float s = 0.f;
    for (int h = 0; h < HNUM; ++h) s += Wpb[t * HNUM + h];
    wpbsum[t] = s;
  }
  if (t < HNUM) {
    float g = softplusf(sc[t]);
    lamBase[t] = -g * kC2;
  }
  __syncthreads();
  if (t == 0) {
    float s = 0.f;
    for (int h = 0; h < HNUM; ++h) s += lamBase[h];
    Gsum[0] = s;
  }
}

// ---------------- d2row[i] = sum_j d[i,j]^2 ------------------------------
__global__ __launch_bounds__(256) void k_d2row(const float* __restrict__ d,
                                               float* __restrict__ d2row) {
  int i = blockIdx.x, t = threadIdx.x;
  const float4* row = (const float4*)(d + (size_t)i * LLEN);
  float4 v = row[t];
  float s = v.x * v.x + v.y * v.y + v.z * v.z + v.w * v.w;
  s = warp_red_sum(s);
  __shared__ float red[4];
  if ((t & 63) == 0) red[t >> 6] = s;
  __syncthreads();
  if (t == 0) d2row[i] = red[0] + red[1] + red[2] + red[3];
}

// ---------------- sum_lp[i] = sum_{j,p} z[i,j,p]*wpbsum[p] ---------------
__global__ __launch_bounds__(256) void k_sumlp(const float* __restrict__ z,
                                               const float* __restrict__ wpbsum,
                                               float* __restrict__ sum_lp) {
  int i = blockIdx.x, t = threadIdx.x;
  const float4* zr = (const float4*)(z + (size_t)i * LLEN * DPP);
  int p4 = t & 15;
  float4 w = ((const float4*)wpbsum)[p4];
  float acc = 0.f;
  for (int k = 0; k < 64; ++k) {
    float4 v = zr[t + (k << 8)];
    acc += v.x * w.x + v.y * w.y + v.z * w.z + v.w * w.w;
  }
  acc = warp_red_sum(acc);
  __shared__ float red[4];
  if ((t & 63) == 0) red[t >> 6] = acc;
  __syncthreads();
  if (t == 0) sum_lp[i] = red[0] + red[1] + red[2] + red[3];
}

// ---------------- generic fp32 SGEMM 64x64 tile, 4x4/thread --------------
template <int K, int LDA, int LDB, int LDC>
__device__ __forceinline__ void gemm_core(const float* __restrict__ A,
                                          const float* __restrict__ B,
                                          float* __restrict__ C, int bm, int bn) {
  __shared__ float As[16][68];
  __shared__ float Bs[16][68];
  const int t = threadIdx.x;
  const int tx = t & 15, ty = t >> 4;
  const int ar = t >> 2, ac = (t & 3) << 2;
  const int bk = t >> 4, bc = (t & 15) << 2;
  float acc[4][4] = {};
  for (int k0 = 0; k0 < K; k0 += 16) {
    float4 av;
    if (k0 + ac + 3 < K) {
      av = *(const float4*)(A + (size_t)(bm + ar) * LDA + k0 + ac);
    } else {
      av.x = (k0 + ac + 0 < K) ? A[(size_t)(bm + ar) * LDA + k0 + ac + 0] : 0.f;
      av.y = (k0 + ac + 1 < K) ? A[(size_t)(bm + ar) * LDA + k0 + ac + 1] : 0.f;
      av.z = (k0 + ac + 2 < K) ? A[(size_t)(bm + ar) * LDA + k0 + ac + 2] : 0.f;
      av.w = (k0 + ac + 3 < K) ? A[(size_t)(bm + ar) * LDA + k0 + ac + 3] : 0.f;
    }
    As[ac + 0][ar] = av.x; As[ac + 1][ar] = av.y;
    As[ac + 2][ar] = av.z; As[ac + 3][ar] = av.w;
    float4 bv;
    if (k0 + bk < K) bv = *(const float4*)(B + (size_t)(k0 + bk) * LDB + bn + bc);
    else { bv.x = bv.y = bv.z = bv.w = 0.f; }
    *(float4*)(&Bs[bk][bc]) = bv;
    __syncthreads();
    #pragma unroll
    for (int kk = 0; kk < 16; ++kk) {
      float4 a4 = *(const float4*)(&As[kk][ty << 2]);
      float4 b4 = *(const float4*)(&Bs[kk][tx << 2]);
      acc[0][0] += a4.x * b4.x; acc[0][1] += a4.x * b4.y; acc[0][2] += a4.x * b4.z; acc[0][3] += a4.x * b4.w;
      acc[1][0] += a4.y * b4.x; acc[1][1] += a4.y * b4.y; acc[1][2] += a4.y * b4.z; acc[1][3] += a4.y * b4.w;
      acc[2][0] += a4.z * b4.x; acc[2][1] += a4.z * b4.y; acc[2][2] += a4.z * b4.z; acc[2][3] += a4.z * b4.w;
      acc[3][0] += a4.w * b4.x; acc[3][1] += a4.w * b4.y; acc[3][2] += a4.w * b4.z; acc[3][3] += a4.w * b4.w;
    }
    __syncthreads();
  }
  #pragma unroll
  for (int ii = 0; ii < 4; ++ii) {
    float4 o4;
    o4.x = acc[ii][0]; o4.y = acc[ii][1]; o4.z = acc[ii][2]; o4.w = acc[ii][3];
    *(float4*)(C + (size_t)(bm + (ty << 2) + ii) * LDC + bn + (tx << 2)) = o4;
  }
}

__global__ __launch_bounds__(256) void k_gemm_qkv(const float* __restrict__ x,
    const float* __restrict__ Wq, const float* __restrict__ Wk,
    const float* __restrict__ Wv, float* __restrict__ q, float* __restrict__ k,
    float* __restrict__ v) {
  int bx = blockIdx.x;
  int mat = bx / 3, bn = (bx % 3) * 64, bm = blockIdx.y * 64;
  const float* B = (mat == 0) ? Wq : ((mat == 1) ? Wk : Wv);
  float* C = (mat == 0) ? q : ((mat == 1) ? k : v);
  gemm_core<1024, 1024, 192, 192>(x, B, C, bm, bn);
}

__global__ __launch_bounds__(256) void k_gemm_feat(const float* __restrict__ feat,
    const float* __restrict__ Wout, float* __restrict__ fgemm) {
  gemm_core<1044, 1044, 1024, 1024>(feat, Wout, fgemm, blockIdx.y * 64, blockIdx.x * 64);
}

// ---------------- Ksum[o] = sum_f xsum[f] * Wk[f,o] ----------------------
__global__ void k_ksum(const float* __restrict__ xsum, const float* __restrict__ Wk,
                       float* __restrict__ Ksum) {
  int o = blockIdx.x * 64 + threadIdx.x;
  float s = 0.f;
  for (int f = 0; f < 1024; ++f) s += xsum[f] * Wk[f * HC + o];
  Ksum[o] = s;
}

// ---------------- xw rows: [ln_sum, lp_sum, ld_sum] ----------------------
__global__ __launch_bounds__(256) void k_xw(const float* __restrict__ q,
    const float* __restrict__ Ksum, const float* __restrict__ sum_lp,
    const float* __restrict__ d2row, const float* __restrict__ Gsum,
    float* __restrict__ xw) {
  __shared__ float KsS[HC];
  if (threadIdx.x < HC) KsS[threadIdx.x] = Ksum[threadIdx.x];
  __syncthreads();
  int i = blockIdx.x * 256 + threadIdx.x;
  const float* qi = q + (size_t)i * HC;
  float s = 0.f;
  #pragma unroll 8
  for (int o = 0; o < HC; ++o) s += qi[o] * KsS[o];
  xw[i] = s * 0.25f;                 // ln_node.sum / sqrt(16)
  xw[1024 + i] = sum_lp[i];
  xw[2048 + i] = d2row[i] * Gsum[0];
}

// ---------------- qw/kw/vw = xw @ {wq,wk,wv} -----------------------------
__global__ __launch_bounds__(256) void k_qkvw(const float* __restrict__ xw,
    const float* __restrict__ wq, const float* __restrict__ wk,
    const float* __restrict__ wv, float* __restrict__ qkvw) {
  int it = blockIdx.x * 256 + threadIdx.x;
  if (it >= 1728) return;
  int mat = it / 576, rem = it % 576, r = rem / HC, o = rem % HC;
  const float* W = (mat == 0) ? wq : ((mat == 1) ? wk : wv);
  const float* xr = xw + r * 1024;
  float s = 0.f;
  for (int f = 0; f < 1024; ++f) s += xr[f] * W[f * HC + o];
  qkvw[it] = s;
}

// ---------------- tiny 3-token attention + LN ----------------------------
__global__ __launch_bounds__(256) void k_tiny(const float* __restrict__ qkvw,
    const float* __restrict__ wlng, const float* __restrict__ wlnb,
    float* __restrict__ yln) {
  __shared__ float qwS[3][HC], kwS[3][HC], vwS[3][HC];
  __shared__ float wxS[HNUM][3][3];
  __shared__ float yS[3][HC];
  __shared__ float muS[3], isS[3];
  int t = threadIdx.x;
  for (int it = t; it < 576; it += 256) {
    int r = it / HC, o = it % HC;
    qwS[r][o] = qkvw[it];
    kwS[r][o] = qkvw[576 + it];
    vwS[r][o] = qkvw[1152 + it];
  }
  __syncthreads();
  if (t < 108) {
    int h = t / 9, r = (t % 9) / 3, k3 = t % 3;
    float s = 0.f;
    #pragma unroll
    for (int c = 0; c < CNUM; ++c) s += qwS[r][h * CNUM + c] * kwS[k3][h * CNUM + c];
    wxS[h][r][k3] = s * 0.25f;
  }
  __syncthreads();
  if (t < 36) {   // softmax over the q axis (axis=2 of (n,h,q,k))
    int h = t / 3, k3 = t % 3;
    float a0 = wxS[h][0][k3], a1 = wxS[h][1][k3], a2 = wxS[h][2][k3];
    float m = fmaxf(a0, fmaxf(a1, a2));
    float e0 = expf(a0 - m), e1 = expf(a1 - m), e2 = expf(a2 - m);
    float inv = 1.f / (e0 + e1 + e2);
    wxS[h][0][k3] = e0 * inv; wxS[h][1][k3] = e1 * inv; wxS[h][2][k3] = e2 * inv;
  }
  __syncthreads();
  for (int it = t; it < 576; it += 256) {
    int r = it / HC, o = it % HC, h = o / CNUM;
    float s = 0.f;
    #pragma unroll
    for (int k3 = 0; k3 < 3; ++k3) s += wxS[h][r][k3] * vwS[k3][o];
    yS[r][o] = s;
  }
  __syncthreads();
  if (t < 3) {
    float m = 0.f;
    for (int o = 0; o < HC; ++o) m += yS[t][o];
    m *= (1.f / HC);
    float vv = 0.f;
    for (int o = 0; o < HC; ++o) { float dd = yS[t][o] - m; vv += dd * dd; }
    vv *= (1.f / HC);
    muS[t] = m; isS[t] = rsqrtf(vv + 1e-5f);
  }
  __syncthreads();
  for (int it = t; it < 576; it += 256) {
    int r = it / HC, o = it % HC;
    yln[it] = (yS[r][o] - muS[r]) * isS[r] * wlng[o] + wlnb[o];
  }
}

// ---------------- hid = relu(yln @ Wa1 + ba1) ----------------------------
__global__ __launch_bounds__(256) void k_hid(const float* __restrict__ yln,
    const float* __restrict__ Wa1, const float* __restrict__ ba1,
    float* __restrict__ hid) {
  int it = blockIdx.x * 256 + threadIdx.x;   // 0..3071
  int r = it >> 10, o = it & 1023;
  __shared__ float yS[HC];
  if (threadIdx.x < HC) yS[threadIdx.x] = yln[r * HC + threadIdx.x];
  __syncthreads();
  float s = ba1[o];
  for (int f = 0; f < HC; ++f) s += yS[f] * Wa1[f * 1024 + o];
  hid[it] = fmaxf(s, 0.f);
}

// ---------------- a,b,c scalars -> folded logit coefficients -------------
__global__ __launch_bounds__(256) void k_abc(const float* __restrict__ hid,
    const float* __restrict__ Wa2, const float* __restrict__ ba2,
    const float* __restrict__ lamBase, float* __restrict__ coefs) {
  __shared__ float redS[3][257];
  int t = threadIdx.x;
  float p0 = 0.f, p1 = 0.f, p2 = 0.f;
  for (int o = t; o < 1024; o += 256) {
    float w = Wa2[o];
    p0 += hid[o] * w; p1 += hid[1024 + o] * w; p2 += hid[2048 + o] * w;
  }
  redS[0][t] = p0; redS[1][t] = p1; redS[2][t] = p2;
  __syncthreads();
  if (t == 0) {
    float y0 = ba2[0], y1 = ba2[0], y2 = ba2[0];
    for (int j = 0; j < 256; ++j) { y0 += redS[0][j]; y1 += redS[1][j]; y2 += redS[2][j]; }
    float a = softplusf(y0);
    float b = softplusf(y1);
    float c = 1.f / (1.f + expf(-softplusf(y2)));
    coefs[0] = kS * a * 0.25f;                 // multiplies q (lnn term incl 1/sqrt(C))
    coefs[1] = kS * b;                          // multiplies lp
    for (int h = 0; h < HNUM; ++h) coefs[2 + h] = kS * c * lamBase[h];  // * d^2
  }
}

// ---------------- main fused row kernel (online softmax + 3 einsums) -----
__global__ __launch_bounds__(512) void k_main(
    const float* __restrict__ z, const float* __restrict__ d,
    const int* __restrict__ mask, const float* __restrict__ q,
    const float* __restrict__ k, const float* __restrict__ v,
    const float* __restrict__ Wpb, const float* __restrict__ p_CB,
    const float* __restrict__ R, const float* __restrict__ tvec,
    const float* __restrict__ coefs, float* __restrict__ feat) {
  const int i = blockIdx.x;
  const int t = threadIdx.x;
  __shared__ float zsS[64][65];      // z tile [jl][p], padded stride 65 (odd)
  __shared__ float eT[HNUM][64];     // logits then exp
  __shared__ float WpbT[HNUM][64];
  __shared__ float qSS[HC];
  __shared__ float d2S[64];
  __shared__ int   maskS[64];
  __shared__ float lamS[HNUM];
  __shared__ float mS[HNUM], sumS[HNUM], scaleS[HNUM];
  __shared__ float aggS[36];

  const float coefB = coefs[1];
  if (t < HC) qSS[t] = q[(size_t)i * HC + t] * coefs[0];
  if (t < HNUM) { lamS[t] = coefs[2 + t]; mS[t] = -INFINITY; sumS[t] = 0.f; }
  if (t < 64) {
    #pragma unroll
    for (int h = 0; h < HNUM; ++h) WpbT[h][t] = Wpb[t * HNUM + h];
  }
  const int maski = mask[i];
  __syncthreads();

  float acc0 = 0.f, acc1 = 0.f;
  const int it0 = t;            // 0..511  -> p2n heads 0..7
  const int it1 = t + 512;      // 512..1023 -> p2n h8..11 / node / aggr

  for (int jt = 0; jt < 16; ++jt) {
    const int j0 = jt * 64;
    {  // stage z tile: 1024 float4s, 2 per thread
      const float4* zr = (const float4*)(z + ((size_t)i * LLEN + j0) * DPP);
      float4 a4 = zr[t];
      float4 b4 = zr[t + 512];
      int r0 = t >> 4, c0 = (t & 15) << 2;
      zsS[r0][c0 + 0] = a4.x; zsS[r0][c0 + 1] = a4.y;
      zsS[r0][c0 + 2] = a4.z; zsS[r0][c0 + 3] = a4.w;
      zsS[r0 + 32][c0 + 0] = b4.x; zsS[r0 + 32][c0 + 1] = b4.y;
      zsS[r0 + 32][c0 + 2] = b4.z; zsS[r0 + 32][c0 + 3] = b4.w;
    }
    if (t < 64) {
      float dd = d[(size_t)i * LLEN + j0 + t];
      d2S[t] = dd * dd;
      maskS[t] = mask[j0 + t];
    }
    __syncthreads();

    // logits for the tile: item = h*64 + jl
    #pragma unroll
    for (int pass = 0; pass < 2; ++pass) {
      int item = t + pass * 512;
      if (item < 768) {
        int h = item >> 6, jl = item & 63;
        const float* kr = k + (size_t)(j0 + jl) * HC + h * CNUM;
        float lnn = 0.f;
        #pragma unroll
        for (int c = 0; c < CNUM; ++c) lnn += qSS[h * CNUM + c] * kr[c];
        float lp = 0.f;
        #pragma unroll 8
        for (int p = 0; p < 64; ++p) lp += zsS[jl][p] * WpbT[h][p];
        float lg = lnn + coefB * lp + d2S[jl] * lamS[h];
        if (maski && !maskS[jl]) lg -= kINF;
        eT[h][jl] = lg;
      }
    }
    __syncthreads();

    // per-head online max/sum update; wave w handles heads w, w+8
    {
      int w = t >> 6, lane = t & 63;
      for (int hh = w; hh < HNUM; hh += 8) {
        float l = eT[hh][lane];
        float m = l;
        #pragma unroll
        for (int o = 32; o > 0; o >>= 1) m = fmaxf(m, __shfl_xor(m, o));
        float mold = mS[hh];
        float mnew = fmaxf(mold, m);
        float e = expf(l - mnew);
        eT[hh][lane] = e;
        float ssum = e;
        #pragma unroll
        for (int o = 32; o > 0; o >>= 1) ssum += __shfl_xor(ssum, o);
        if (lane == 0) {
          float sc = expf(mold - mnew);   // expf(-inf)=0 on first tile
          sumS[hh] = sumS[hh] * sc + ssum;
          mS[hh] = mnew;
          scaleS[hh] = sc;
        }
      }
    }
    __syncthreads();

    // accumulate (rescale-then-add)
    {
      int h = it0 >> 6, p = it0 & 63;
      float s = 0.f;
      #pragma unroll 8
      for (int jl = 0; jl < 64; ++jl) s += eT[h][jl] * zsS[jl][p];
      acc0 = acc0 * scaleS[h] + s;
    }
    if (it1 < 996) {
      if (it1 < 768) {
        int h = it1 >> 6, p = it1 & 63;
        float s = 0.f;
        #pragma unroll 8
        for (int jl = 0; jl < 64; ++jl) s += eT[h][jl] * zsS[jl][p];
        acc1 = acc1 * scaleS[h] + s;
      } else if (it1 < 960) {
        int e2 = it1 - 768, h = e2 >> 4, c = e2 & 15;
        float s = 0.f;
        for (int jl = 0; jl < 64; ++jl)
          s += eT[h][jl] * v[(size_t)(j0 + jl) * HC + h * CNUM + c];
        acc1 = acc1 * scaleS[h] + s;
      } else {
        int e2 = it1 - 960, h = e2 / 3, c = e2 % 3;
        float s = 0.f;
        for (int jl = 0; jl < 64; ++jl)
          s += eT[h][jl] * p_CB[(size_t)(j0 + jl) * 3 + c];
        acc1 = acc1 * scaleS[h] + s;
      }
    }
    __syncthreads();  // before next tile overwrites zsS/eT
  }

  // epilogue: divide by partition sums, write feat
  const size_t base = (size_t)i * 1044;
  feat[base + it0] = acc0 / sumS[it0 >> 6];
  if (it1 < 996) {
    if (it1 < 768)      feat[base + it1] = acc1 / sumS[it1 >> 6];
    else if (it1 < 960) feat[base + it1] = acc1 / sumS[(it1 - 768) >> 4];
    else                aggS[it1 - 960]  = acc1 / sumS[(it1 - 960) / 3];
  }
  __syncthreads();
  if (t < HNUM) {
    int h = t;
    float a0 = aggS[h * 3 + 0] - tvec[(size_t)i * 3 + 0];
    float a1 = aggS[h * 3 + 1] - tvec[(size_t)i * 3 + 1];
    float a2 = aggS[h * 3 + 2] - tvec[(size_t)i * 3 + 2];
    const float* Ri = R + (size_t)i * 9;
    float px = Ri[0] * a0 + Ri[3] * a1 + Ri[6] * a2;
    float py = Ri[1] * a0 + Ri[4] * a1 + Ri[7] * a2;
    float pz = Ri[2] * a0 + Ri[5] * a1 + Ri[8] * a2;
    float dist = sqrtf(px * px + py * py + pz * pz);
    float invd = 1.f / (dist + 1e-4f);
    feat[base + 960 + h * 3 + 0] = px;
    feat[base + 960 + h * 3 + 1] = py;
    feat[base + 960 + h * 3 + 2] = pz;
    feat[base + 996 + h] = dist;
    feat[base + 1008 + h * 3 + 0] = px * invd;
    feat[base + 1008 + h * 3 + 1] = py * invd;
    feat[base + 1008 + h * 3 + 2] = pz * invd;
  }
}

// ---------------- final: out = LN(x + mask*(fgemm + bout)) ---------------
__global__ __launch_bounds__(256) void k_final(const float* __restrict__ x,
    const float* __restrict__ fgemm, const float* __restrict__ bout,
    const int* __restrict__ mask, const float* __restrict__ g,
    const float* __restrict__ b, float* __restrict__ out) {
  int i = blockIdx.x, t = threadIdx.x;
  int maski = mask[i];
  float vals[4];
  float s = 0.f;
  #pragma unroll
  for (int k4 = 0; k4 < 4; ++k4) {
    int c = t + k4 * 256;
    float f = maski ? (fgemm[(size_t)i * DNN + c] + bout[c]) : 0.f;
    vals[k4] = x[(size_t)i * DNN + c] + f;
    s += vals[k4];
  }
  s = warp_red_sum(s);
  __shared__ float red[4];
  __shared__ float mu, istd;
  if ((t & 63) == 0) red[t >> 6] = s;
  __syncthreads();
  if (t == 0) mu = (red[0] + red[1] + red[2] + red[3]) * (1.f / DNN);
  __syncthreads();
  float vs = 0.f;
  #pragma unroll
  for (int k4 = 0; k4 < 4; ++k4) { float dd = vals[k4] - mu; vs += dd * dd; }
  vs = warp_red_sum(vs);
  if ((t & 63) == 0) red[t >> 6] = vs;
  __syncthreads();
  if (t == 0) istd = rsqrtf((red[0] + red[1] + red[2] + red[3]) * (1.f / DNN) + 1e-5f);
  __syncthreads();
  #pragma unroll
  for (int k4 = 0; k4 < 4; ++k4) {
    int c = t + k4 * 256;
    out[(size_t)i * DNN + c] = (vals[k4] - mu) * istd * g[c] + b[c];
  }
}

extern "C" void kernel_launch(void* const* d_in, const int* in_sizes, int n_in,
                              void* d_out, int out_size, void* d_ws, size_t ws_size,
                              hipStream_t stream) {
  const float* R      = (const float*)d_in[0];
  const float* tvec   = (const float*)d_in[1];
  const float* p_CB   = (const float*)d_in[2];
  const float* x      = (const float*)d_in[3];
  const float* z      = (const float*)d_in[4];
  const float* dmat   = (const float*)d_in[5];
  const int*   mask   = (const int*)d_in[6];
  const float* Wq     = (const float*)d_in[7];
  const float* Wk     = (const float*)d_in[8];
  const float* Wv     = (const float*)d_in[9];
  const float* Wpb    = (const float*)d_in[10];
  const float* spc    = (const float*)d_in[11];
  const float* Wout   = (const float*)d_in[12];
  const float* bout   = (const float*)d_in[13];
  const float* lng    = (const float*)d_in[14];
  const float* lnb    = (const float*)d_in[15];
  const float* wq     = (const float*)d_in[16];
  const float* wk     = (const float*)d_in[17];
  const float* wv     = (const float*)d_in[18];
  const float* wlng   = (const float*)d_in[19];
  const float* wlnb   = (const float*)d_in[20];
  const float* Wa1    = (const float*)d_in[21];
  const float* ba1    = (const float*)d_in[22];
  const float* Wa2    = (const float*)d_in[23];
  const float* ba2    = (const float*)d_in[24];
  float* out = (float*)d_out;

  float* p = (float*)d_ws;
  auto alloc = [&](size_t n) { float* r = p; p += n; return r; };
  float* q_     = alloc(196608);   // 1024*192
  float* k_     = alloc(196608);
  float* v_     = alloc(196608);
  float* feat   = alloc(1069056);  // 1024*1044
  float* fgemm  = alloc(1048576);  // 1024*1024
  float* xsum   = alloc(1024);
  float* d2row  = alloc(1024);
  float* sum_lp = alloc(1024);
  float* wpbsum = alloc(64);
  float* lamBase= alloc(16);
  float* Gsum   = alloc(4);
  float* coefs  = alloc(16);
  float* Ksum   = alloc(192);
  float* xw     = alloc(3072);
  float* qkvw   = alloc(1728);
  float* yln    = alloc(576);
  float* hid    = alloc(3072);

  hipMemsetAsync(xsum, 0, 1024 * sizeof(float), stream);

  k_gemm_qkv<<<dim3(9, 16), 256, 0, stream>>>(x, Wq, Wk, Wv, q_, k_, v_);
  k_xsum<<<64, 256, 0, stream>>>(x, xsum);
  k_misc<<<1, 64, 0, stream>>>(Wpb, spc, wpbsum, lamBase, Gsum);
  k_d2row<<<1024, 256, 0, stream>>>(dmat, d2row);
  k_sumlp<<<1024, 256, 0, stream>>>(z, wpbsum, sum_lp);
  k_ksum<<<3, 64, 0, stream>>>(xsum, Wk, Ksum);
  k_xw<<<4, 256, 0, stream>>>(q_, Ksum, sum_lp, d2row, Gsum, xw);
  k_qkvw<<<7, 256, 0, stream>>>(xw, wq, wk, wv, qkvw);
  k_tiny<<<1, 256, 0, stream>>>(qkvw, wlng, wlnb, yln);
  k_hid<<<12, 256, 0, stream>>>(yln, Wa1, ba1, hid);
  k_abc<<<1, 256, 0, stream>>>(hid, Wa2, ba2, lamBase, coefs);
  k_main<<<1024, 512, 0, stream>>>(z, dmat, mask, q_, k_, v_, Wpb, p_CB, R, tvec,
                                   coefs, feat);
  k_gemm_feat<<<dim3(16, 16), 256, 0, stream>>>(feat, Wout, fgemm);
  k_final<<<1024, 256, 0, stream>>>(x, fgemm, bout, mask, lng, lnb, out);
}

// Round 3
// 1022.036 us; speedup vs baseline: 1.3035x; 1.3035x over previous
//
#include <hip/hip_runtime.h>
#include <hip/hip_bf16.h>
#include <math.h>

// N=1, L=1024, DN=1024, DP=64, H=12, C=16
#define LLEN 1024
#define DNN  1024
#define HNUM 12
#define CNUM 16
#define HC   192
#define DPP  64
#define SPLITJ 4

constexpr float kINF = 100000.0f;
constexpr float kC2  = 0.23570226039551584f;  // sqrt(2/9)/2
constexpr float kS   = 0.57735026918962576f;  // sqrt(1/3)

typedef short bf8v __attribute__((ext_vector_type(8)));
typedef float f32x4 __attribute__((ext_vector_type(4)));

__device__ __forceinline__ float softplusf(float x) {
  return fmaxf(x, 0.f) + log1pf(expf(-fabsf(x)));
}

__device__ __forceinline__ float warp_red_sum(float v) {
  #pragma unroll
  for (int o = 32; o > 0; o >>= 1) v += __shfl_down(v, o);
  return v;
}

__device__ __forceinline__ short f2bf(float f) {
  union { float f; unsigned u; } c; c.f = f;
  unsigned r = c.u + 0x7FFFu + ((c.u >> 16) & 1u);   // RNE
  return (short)(r >> 16);
}

// ---------------- xsum[f] = sum_rows x[r][f] (for Ksum = xsum @ Wk) -------
__global__ __launch_bounds__(256) void k_xsum(const float* __restrict__ x,
                                              float* __restrict__ xsum) {
  int c0 = threadIdx.x;
  int r0 = blockIdx.x * 16;
  float acc[4] = {0.f, 0.f, 0.f, 0.f};
  for (int r = 0; r < 16; ++r) {
    const float* row = x + (size_t)(r0 + r) * DNN;
    #pragma unroll
    for (int kq = 0; kq < 4; ++kq) acc[kq] += row[c0 + kq * 256];
  }
  #pragma unroll
  for (int kq = 0; kq < 4; ++kq) atomicAdd(&xsum[c0 + kq * 256], acc[kq]);
}

// ---------------- wpbsum, lamBase, Gsum ----------------------------------
__global__ void k_misc(const float* __restrict__ Wpb, const float* __restrict__ sc,
                       float* __restrict__ wpbsum, float* __restrict__ lamBase,
                       float* __restrict__ Gsum) {
  int t = threadIdx.x;
  if (t < 64) {
    float s = 0.f;
    for (int h = 0; h < HNUM; ++h) s += Wpb[t * HNUM + h];
    wpbsum[t] = s;
  }
  if (t < HNUM) {
    float g = softplusf(sc[t]);
    lamBase[t] = -g * kC2;
  }
  __syncthreads();
  if (t == 0) {
    float s = 0.f;
    for (int h = 0; h < HNUM; ++h) s += lamBase[h];
    Gsum[0] = s;
  }
}

// ---------------- d2row[i] = sum_j d[i,j]^2 ------------------------------
__global__ __launch_bounds__(256) void k_d2row(const float* __restrict__ d,
                                               float* __restrict__ d2row) {
  int i = blockIdx.x, t = threadIdx.x;
  const float4* row = (const float4*)(d + (size_t)i * LLEN);
  float4 v = row[t];
  float s = v.x * v.x + v.y * v.y + v.z * v.z + v.w * v.w;
  s = warp_red_sum(s);
  __shared__ float red[4];
  if ((t & 63) == 0) red[t >> 6] = s;
  __syncthreads();
  if (t == 0) d2row[i] = red[0] + red[1] + red[2] + red[3];
}

// ---------------- sum_lp[i] = sum_{j,p} z[i,j,p]*wpbsum[p] ---------------
__global__ __launch_bounds__(256) void k_sumlp(const float* __restrict__ z,
                                               const float* __restrict__ wpbsum,
                                               float* __restrict__ sum_lp) {
  int i = blockIdx.x, t = threadIdx.x;
  const float4* zr = (const float4*)(z + (size_t)i * LLEN * DPP);
  int p4 = t & 15;
  float4 w = ((const float4*)wpbsum)[p4];
  float acc = 0.f;
  for (int k = 0; k < 64; ++k) {
    float4 v = zr[t + (k << 8)];
    acc += v.x * w.x + v.y * w.y + v.z * w.z + v.w * w.w;
  }
  acc = warp_red_sum(acc);
  __shared__ float red[4];
  if ((t & 63) == 0) red[t >> 6] = acc;
  __syncthreads();
  if (t == 0) sum_lp[i] = red[0] + red[1] + red[2] + red[3];
}

// ---------------- bf16 MFMA GEMM: C(MxN,f32) = A(MxK,f32) * B(KxN,f32) ---
// 64x64 tile, 256 threads = 4 waves, each wave a 32x32 quadrant (2x2 frags).
// f32 -> bf16 conversion happens during LDS staging.
template <int K, int LDA, int LDB, int LDC>
__device__ __forceinline__ void mfma_gemm(const float* __restrict__ A,
                                          const float* __restrict__ B,
                                          float* __restrict__ C, int bm, int bn) {
  __shared__ short As[64][40];   // [row][k], stride 40 -> 80B rows (16B aligned)
  __shared__ short Bs[64][40];   // [col][k]
  const int t = threadIdx.x;
  const int l = t & 63, w = t >> 6;
  const int wr = (w >> 1) * 32, wc = (w & 1) * 32;
  const int lr = l & 15, kg = l >> 4;          // frag: row/col = lr, k-base = kg*8
  const int arow = t >> 2, akp = (t & 3) * 8;  // A staging
  const int bkk = t >> 4, bc4 = (t & 15) * 4;  // B staging
  f32x4 acc[2][2];
  #pragma unroll
  for (int a = 0; a < 2; ++a)
    #pragma unroll
    for (int b = 0; b < 2; ++b) { acc[a][b][0]=0.f; acc[a][b][1]=0.f; acc[a][b][2]=0.f; acc[a][b][3]=0.f; }

  for (int k0 = 0; k0 < K; k0 += 32) {
    {  // stage A: 64x32 f32 -> bf16
      const float* ap = A + (size_t)(bm + arow) * LDA + k0 + akp;
      bf8v v8;
      if (k0 + akp + 8 <= K) {
        float4 p0 = *(const float4*)ap;
        float4 p1 = *(const float4*)(ap + 4);
        v8[0] = f2bf(p0.x); v8[1] = f2bf(p0.y); v8[2] = f2bf(p0.z); v8[3] = f2bf(p0.w);
        v8[4] = f2bf(p1.x); v8[5] = f2bf(p1.y); v8[6] = f2bf(p1.z); v8[7] = f2bf(p1.w);
      } else {
        #pragma unroll
        for (int j = 0; j < 8; ++j) v8[j] = (k0 + akp + j < K) ? f2bf(ap[j]) : (short)0;
      }
      *(bf8v*)&As[arow][akp] = v8;
    }
    #pragma unroll
    for (int half = 0; half < 2; ++half) {  // stage B transposed: Bs[col][k]
      int kk = bkk + half * 16;
      float4 g = {0.f, 0.f, 0.f, 0.f};
      if (k0 + kk < K) g = *(const float4*)(B + (size_t)(k0 + kk) * LDB + bn + bc4);
      Bs[bc4 + 0][kk] = f2bf(g.x);
      Bs[bc4 + 1][kk] = f2bf(g.y);
      Bs[bc4 + 2][kk] = f2bf(g.z);
      Bs[bc4 + 3][kk] = f2bf(g.w);
    }
    __syncthreads();
    bf8v af0 = *(bf8v*)&As[wr + lr][kg * 8];
    bf8v af1 = *(bf8v*)&As[wr + 16 + lr][kg * 8];
    bf8v bf0 = *(bf8v*)&Bs[wc + lr][kg * 8];
    bf8v bf1 = *(bf8v*)&Bs[wc + 16 + lr][kg * 8];
    acc[0][0] = __builtin_amdgcn_mfma_f32_16x16x32_bf16(af0, bf0, acc[0][0], 0, 0, 0);
    acc[0][1] = __builtin_amdgcn_mfma_f32_16x16x32_bf16(af0, bf1, acc[0][1], 0, 0, 0);
    acc[1][0] = __builtin_amdgcn_mfma_f32_16x16x32_bf16(af1, bf0, acc[1][0], 0, 0, 0);
    acc[1][1] = __builtin_amdgcn_mfma_f32_16x16x32_bf16(af1, bf1, acc[1][1], 0, 0, 0);
    __syncthreads();
  }
  // epilogue: D[row=(l>>4)*4+r][col=l&15] per frag
  #pragma unroll
  for (int fr = 0; fr < 2; ++fr)
    #pragma unroll
    for (int fc = 0; fc < 2; ++fc) {
      float* cp = C + (size_t)(bm + wr + fr * 16 + kg * 4) * LDC + bn + wc + fc * 16 + lr;
      #pragma unroll
      for (int r = 0; r < 4; ++r) cp[(size_t)r * LDC] = acc[fr][fc][r];
    }
}

__global__ __launch_bounds__(256) void k_gemm_qkv(const float* __restrict__ x,
    const float* __restrict__ Wq, const float* __restrict__ Wk,
    const float* __restrict__ Wv, float* __restrict__ q, float* __restrict__ k,
    float* __restrict__ v) {
  int bx = blockIdx.x;
  int mat = bx / 3, bn = (bx % 3) * 64, bm = blockIdx.y * 64;
  const float* B = (mat == 0) ? Wq : ((mat == 1) ? Wk : Wv);
  float* C = (mat == 0) ? q : ((mat == 1) ? k : v);
  mfma_gemm<1024, 1024, HC, HC>(x, B, C, bm, bn);
}

__global__ __launch_bounds__(256) void k_gemm_feat(const float* __restrict__ feat,
    const float* __restrict__ Wout, float* __restrict__ fgemm) {
  mfma_gemm<1044, 1044, 1024, 1024>(feat, Wout, fgemm, blockIdx.y * 64, blockIdx.x * 64);
}

// ---------------- Ksum[o] = sum_f xsum[f] * Wk[f,o] ----------------------
__global__ void k_ksum(const float* __restrict__ xsum, const float* __restrict__ Wk,
                       float* __restrict__ Ksum) {
  int o = blockIdx.x * 64 + threadIdx.x;
  float s = 0.f;
  for (int f = 0; f < 1024; ++f) s += xsum[f] * Wk[f * HC + o];
  Ksum[o] = s;
}

// ---------------- xw rows: [ln_sum, lp_sum, ld_sum] ----------------------
__global__ __launch_bounds__(256) void k_xw(const float* __restrict__ q,
    const float* __restrict__ Ksum, const float* __restrict__ sum_lp,
    const float* __restrict__ d2row, const float* __restrict__ Gsum,
    float* __restrict__ xw) {
  __shared__ float KsS[HC];
  if (threadIdx.x < HC) KsS[threadIdx.x] = Ksum[threadIdx.x];
  __syncthreads();
  int i = blockIdx.x * 256 + threadIdx.x;
  const float* qi = q + (size_t)i * HC;
  float s = 0.f;
  #pragma unroll 8
  for (int o = 0; o < HC; ++o) s += qi[o] * KsS[o];
  xw[i] = s * 0.25f;                 // ln_node.sum / sqrt(16)
  xw[1024 + i] = sum_lp[i];
  xw[2048 + i] = d2row[i] * Gsum[0];
}

// ---------------- qw/kw/vw = xw @ {wq,wk,wv} -----------------------------
__global__ __launch_bounds__(256) void k_qkvw(const float* __restrict__ xw,
    const float* __restrict__ wq, const float* __restrict__ wk,
    const float* __restrict__ wv, float* __restrict__ qkvw) {
  int it = blockIdx.x * 256 + threadIdx.x;
  if (it >= 1728) return;
  int mat = it / 576, rem = it % 576, r = rem / HC, o = rem % HC;
  const float* W = (mat == 0) ? wq : ((mat == 1) ? wk : wv);
  const float* xr = xw + r * 1024;
  float s = 0.f;
  for (int f = 0; f < 1024; ++f) s += xr[f] * W[f * HC + o];
  qkvw[it] = s;
}

// ---------------- tiny 3-token attention + LN ----------------------------
__global__ __launch_bounds__(256) void k_tiny(const float* __restrict__ qkvw,
    const float* __restrict__ wlng, const float* __restrict__ wlnb,
    float* __restrict__ yln) {
  __shared__ float qwS[3][HC], kwS[3][HC], vwS[3][HC];
  __shared__ float wxS[HNUM][3][3];
  __shared__ float yS[3][HC];
  __shared__ float muS[3], isS[3];
  int t = threadIdx.x;
  for (int it = t; it < 576; it += 256) {
    int r = it / HC, o = it % HC;
    qwS[r][o] = qkvw[it];
    kwS[r][o] = qkvw[576 + it];
    vwS[r][o] = qkvw[1152 + it];
  }
  __syncthreads();
  if (t < 108) {
    int h = t / 9, r = (t % 9) / 3, k3 = t % 3;
    float s = 0.f;
    #pragma unroll
    for (int c = 0; c < CNUM; ++c) s += qwS[r][h * CNUM + c] * kwS[k3][h * CNUM + c];
    wxS[h][r][k3] = s * 0.25f;
  }
  __syncthreads();
  if (t < 36) {   // softmax over the q axis (axis=2 of (n,h,q,k))
    int h = t / 3, k3 = t % 3;
    float a0 = wxS[h][0][k3], a1 = wxS[h][1][k3], a2 = wxS[h][2][k3];
    float m = fmaxf(a0, fmaxf(a1, a2));
    float e0 = expf(a0 - m), e1 = expf(a1 - m), e2 = expf(a2 - m);
    float inv = 1.f / (e0 + e1 + e2);
    wxS[h][0][k3] = e0 * inv; wxS[h][1][k3] = e1 * inv; wxS[h][2][k3] = e2 * inv;
  }
  __syncthreads();
  for (int it = t; it < 576; it += 256) {
    int r = it / HC, o = it % HC, h = o / CNUM;
    float s = 0.f;
    #pragma unroll
    for (int k3 = 0; k3 < 3; ++k3) s += wxS[h][r][k3] * vwS[k3][o];
    yS[r][o] = s;
  }
  __syncthreads();
  if (t < 3) {
    float m = 0.f;
    for (int o = 0; o < HC; ++o) m += yS[t][o];
    m *= (1.f / HC);
    float vv = 0.f;
    for (int o = 0; o < HC; ++o) { float dd = yS[t][o] - m; vv += dd * dd; }
    vv *= (1.f / HC);
    muS[t] = m; isS[t] = rsqrtf(vv + 1e-5f);
  }
  __syncthreads();
  for (int it = t; it < 576; it += 256) {
    int r = it / HC, o = it % HC;
    yln[it] = (yS[r][o] - muS[r]) * isS[r] * wlng[o] + wlnb[o];
  }
}

// ---------------- hid = relu(yln @ Wa1 + ba1) ----------------------------
__global__ __launch_bounds__(256) void k_hid(const float* __restrict__ yln,
    const float* __restrict__ Wa1, const float* __restrict__ ba1,
    float* __restrict__ hid) {
  int it = blockIdx.x * 256 + threadIdx.x;   // 0..3071
  int r = it >> 10, o = it & 1023;
  __shared__ float yS[HC];
  if (threadIdx.x < HC) yS[threadIdx.x] = yln[r * HC + threadIdx.x];
  __syncthreads();
  float s = ba1[o];
  for (int f = 0; f < HC; ++f) s += yS[f] * Wa1[f * 1024 + o];
  hid[it] = fmaxf(s, 0.f);
}

// ---------------- a,b,c scalars -> folded logit coefficients -------------
__global__ __launch_bounds__(256) void k_abc(const float* __restrict__ hid,
    const float* __restrict__ Wa2, const float* __restrict__ ba2,
    const float* __restrict__ lamBase, float* __restrict__ coefs) {
  __shared__ float redS[3][257];
  int t = threadIdx.x;
  float p0 = 0.f, p1 = 0.f, p2 = 0.f;
  for (int o = t; o < 1024; o += 256) {
    float w = Wa2[o];
    p0 += hid[o] * w; p1 += hid[1024 + o] * w; p2 += hid[2048 + o] * w;
  }
  redS[0][t] = p0; redS[1][t] = p1; redS[2][t] = p2;
  __syncthreads();
  if (t == 0) {
    float y0 = ba2[0], y1 = ba2[0], y2 = ba2[0];
    for (int j = 0; j < 256; ++j) { y0 += redS[0][j]; y1 += redS[1][j]; y2 += redS[2][j]; }
    float a = softplusf(y0);
    float b = softplusf(y1);
    float c = 1.f / (1.f + expf(-softplusf(y2)));
    coefs[0] = kS * a * 0.25f;                 // multiplies q (lnn term incl 1/sqrt(C))
    coefs[1] = kS * b;                          // multiplies lp
    for (int h = 0; h < HNUM; ++h) coefs[2 + h] = kS * c * lamBase[h];  // * d^2
  }
}

// ---------------- main fused kernel, split over j (flash-decoding) -------
// grid (L, SPLITJ). Each block handles 256 j's (4 tiles of 64) for row i and
// writes unnormalized partial accumulators + per-head (m, sum) to pacc.
__global__ __launch_bounds__(512) void k_main(
    const float* __restrict__ z, const float* __restrict__ d,
    const int* __restrict__ mask, const float* __restrict__ q,
    const float* __restrict__ k, const float* __restrict__ v,
    const float* __restrict__ Wpb, const float* __restrict__ p_CB,
    const float* __restrict__ coefs, float* __restrict__ pacc) {
  const int i = blockIdx.x;
  const int s = blockIdx.y;
  const int t = threadIdx.x;
  const int jbase = s * (LLEN / SPLITJ);   // 256 j's per split
  __shared__ float zsS[64][65];      // z tile [jl][p], padded stride 65
  __shared__ float eT[HNUM][64];     // logits then exp
  __shared__ float WpbT[HNUM][64];
  __shared__ float qSS[HC];
  __shared__ float d2S[64];
  __shared__ int   maskS[64];
  __shared__ float lamS[HNUM];
  __shared__ float mS[HNUM], sumS[HNUM], scaleS[HNUM];

  const float coefB = coefs[1];
  if (t < HC) qSS[t] = q[(size_t)i * HC + t] * coefs[0];
  if (t < HNUM) { lamS[t] = coefs[2 + t]; mS[t] = -INFINITY; sumS[t] = 0.f; }
  if (t < 64) {
    #pragma unroll
    for (int h = 0; h < HNUM; ++h) WpbT[h][t] = Wpb[t * HNUM + h];
  }
  const int maski = mask[i];
  const float4* zr = (const float4*)(z + ((size_t)i * LLEN + jbase) * DPP);

  // prefetch tile 0 into registers
  float4 a4 = zr[t], b4 = zr[t + 512];
  float dv = 0.f; int mv = 0;
  if (t < 64) {
    dv = d[(size_t)i * LLEN + jbase + t];
    mv = mask[jbase + t];
  }
  __syncthreads();

  float acc0 = 0.f, acc1 = 0.f;
  const int it0 = t;            // 0..511  -> p2n heads 0..7
  const int it1 = t + 512;      // 512..1023 -> p2n h8..11 / node / aggr

  for (int jt = 0; jt < LLEN / SPLITJ / 64; ++jt) {
    const int j0 = jbase + jt * 64;
    {  // write prefetched tile to LDS
      int r0 = t >> 4, c0 = (t & 15) << 2;
      zsS[r0][c0 + 0] = a4.x; zsS[r0][c0 + 1] = a4.y;
      zsS[r0][c0 + 2] = a4.z; zsS[r0][c0 + 3] = a4.w;
      zsS[r0 + 32][c0 + 0] = b4.x; zsS[r0 + 32][c0 + 1] = b4.y;
      zsS[r0 + 32][c0 + 2] = b4.z; zsS[r0 + 32][c0 + 3] = b4.w;
      if (t < 64) { d2S[t] = dv * dv; maskS[t] = mv; }
    }
    __syncthreads();
    if (jt + 1 < LLEN / SPLITJ / 64) {  // issue next-tile loads (latency hidden)
      const float4* zn = zr + (size_t)(jt + 1) * 1024;
      a4 = zn[t]; b4 = zn[t + 512];
      if (t < 64) {
        dv = d[(size_t)i * LLEN + j0 + 64 + t];
        mv = mask[j0 + 64 + t];
      }
    }

    // logits for the tile: item = h*64 + jl
    #pragma unroll
    for (int pass = 0; pass < 2; ++pass) {
      int item = t + pass * 512;
      if (item < 768) {
        int h = item >> 6, jl = item & 63;
        const float* kr = k + (size_t)(j0 + jl) * HC + h * CNUM;
        float lnn = 0.f;
        #pragma unroll
        for (int c = 0; c < CNUM; ++c) lnn += qSS[h * CNUM + c] * kr[c];
        float lp = 0.f;
        #pragma unroll 8
        for (int p = 0; p < 64; ++p) lp += zsS[jl][p] * WpbT[h][p];
        float lg = lnn + coefB * lp + d2S[jl] * lamS[h];
        if (maski && !maskS[jl]) lg -= kINF;
        eT[h][jl] = lg;
      }
    }
    __syncthreads();

    // per-head online max/sum update; wave w handles heads w, w+8
    {
      int w = t >> 6, lane = t & 63;
      for (int hh = w; hh < HNUM; hh += 8) {
        float l = eT[hh][lane];
        float m = l;
        #pragma unroll
        for (int o = 32; o > 0; o >>= 1) m = fmaxf(m, __shfl_xor(m, o));
        float mold = mS[hh];
        float mnew = fmaxf(mold, m);
        float e = expf(l - mnew);
        eT[hh][lane] = e;
        float ssum = e;
        #pragma unroll
        for (int o = 32; o > 0; o >>= 1) ssum += __shfl_xor(ssum, o);
        if (lane == 0) {
          float sc = expf(mold - mnew);   // expf(-inf)=0 on first tile
          sumS[hh] = sumS[hh] * sc + ssum;
          mS[hh] = mnew;
          scaleS[hh] = sc;
        }
      }
    }
    __syncthreads();

    // accumulate (rescale-then-add)
    {
      int h = it0 >> 6, p = it0 & 63;
      float ss = 0.f;
      #pragma unroll 8
      for (int jl = 0; jl < 64; ++jl) ss += eT[h][jl] * zsS[jl][p];
      acc0 = acc0 * scaleS[h] + ss;
    }
    if (it1 < 996) {
      if (it1 < 768) {
        int h = it1 >> 6, p = it1 & 63;
        float ss = 0.f;
        #pragma unroll 8
        for (int jl = 0; jl < 64; ++jl) ss += eT[h][jl] * zsS[jl][p];
        acc1 = acc1 * scaleS[h] + ss;
      } else if (it1 < 960) {
        int e2 = it1 - 768, h = e2 >> 4, c = e2 & 15;
        float ss = 0.f;
        for (int jl = 0; jl < 64; ++jl)
          ss += eT[h][jl] * v[(size_t)(j0 + jl) * HC + h * CNUM + c];
        acc1 = acc1 * scaleS[h] + ss;
      } else {
        int e2 = it1 - 960, h = e2 / 3, c = e2 % 3;
        float ss = 0.f;
        for (int jl = 0; jl < 64; ++jl)
          ss += eT[h][jl] * p_CB[(size_t)(j0 + jl) * 3 + c];
        acc1 = acc1 * scaleS[h] + ss;
      }
    }
    __syncthreads();  // before next tile overwrites zsS/eT
  }

  // write partials (unnormalized, relative to local running max)
  float* part = pacc + ((size_t)i * SPLITJ + s) * 1024;
  part[it0] = acc0;
  if (it1 < 996) part[it1] = acc1;
  if (t < HNUM) { part[996 + t] = mS[t]; part[1008 + t] = sumS[t]; }
}

// ---------------- merge split-j partials -> feat -------------------------
__global__ __launch_bounds__(256) void k_merge(const float* __restrict__ pacc,
    const float* __restrict__ R, const float* __restrict__ tvec,
    float* __restrict__ feat) {
  const int i = blockIdx.x, t = threadIdx.x;
  __shared__ float wS[SPLITJ][HNUM];
  __shared__ float dInv[HNUM];
  __shared__ float aggS[36];
  const float* p0 = pacc + (size_t)i * SPLITJ * 1024;
  if (t < HNUM) {
    float M = -INFINITY;
    #pragma unroll
    for (int s = 0; s < SPLITJ; ++s) M = fmaxf(M, p0[s * 1024 + 996 + t]);
    float den = 0.f;
    #pragma unroll
    for (int s = 0; s < SPLITJ; ++s) {
      float w = expf(p0[s * 1024 + 996 + t] - M);
      wS[s][t] = w;
      den += p0[s * 1024 + 1008 + t] * w;
    }
    dInv[t] = 1.f / den;
  }
  __syncthreads();
  const size_t base = (size_t)i * 1044;
  for (int it = t; it < 996; it += 256) {
    int h = (it < 768) ? (it >> 6) : ((it < 960) ? ((it - 768) >> 4) : ((it - 960) / 3));
    float acc = 0.f;
    #pragma unroll
    for (int s = 0; s < SPLITJ; ++s) acc += p0[s * 1024 + it] * wS[s][h];
    acc *= dInv[h];
    if (it < 960) feat[base + it] = acc;
    else aggS[it - 960] = acc;
  }
  __syncthreads();
  if (t < HNUM) {
    int h = t;
    float a0 = aggS[h * 3 + 0] - tvec[(size_t)i * 3 + 0];
    float a1 = aggS[h * 3 + 1] - tvec[(size_t)i * 3 + 1];
    float a2 = aggS[h * 3 + 2] - tvec[(size_t)i * 3 + 2];
    const float* Ri = R + (size_t)i * 9;
    float px = Ri[0] * a0 + Ri[3] * a1 + Ri[6] * a2;
    float py = Ri[1] * a0 + Ri[4] * a1 + Ri[7] * a2;
    float pz = Ri[2] * a0 + Ri[5] * a1 + Ri[8] * a2;
    float dist = sqrtf(px * px + py * py + pz * pz);
    float invd = 1.f / (dist + 1e-4f);
    feat[base + 960 + h * 3 + 0] = px;
    feat[base + 960 + h * 3 + 1] = py;
    feat[base + 960 + h * 3 + 2] = pz;
    feat[base + 996 + h] = dist;
    feat[base + 1008 + h * 3 + 0] = px * invd;
    feat[base + 1008 + h * 3 + 1] = py * invd;
    feat[base + 1008 + h * 3 + 2] = pz * invd;
  }
}

// ---------------- final: out = LN(x + mask*(fgemm + bout)) ---------------
__global__ __launch_bounds__(256) void k_final(const float* __restrict__ x,
    const float* __restrict__ fgemm, const float* __restrict__ bout,
    const int* __restrict__ mask, const float* __restrict__ g,
    const float* __restrict__ b, float* __restrict__ out) {
  int i = blockIdx.x, t = threadIdx.x;
  int maski = mask[i];
  float vals[4];
  float s = 0.f;
  #pragma unroll
  for (int k4 = 0; k4 < 4; ++k4) {
    int c = t + k4 * 256;
    float f = maski ? (fgemm[(size_t)i * DNN + c] + bout[c]) : 0.f;
    vals[k4] = x[(size_t)i * DNN + c] + f;
    s += vals[k4];
  }
  s = warp_red_sum(s);
  __shared__ float red[4];
  __shared__ float mu, istd;
  if ((t & 63) == 0) red[t >> 6] = s;
  __syncthreads();
  if (t == 0) mu = (red[0] + red[1] + red[2] + red[3]) * (1.f / DNN);
  __syncthreads();
  float vs = 0.f;
  #pragma unroll
  for (int k4 = 0; k4 < 4; ++k4) { float dd = vals[k4] - mu; vs += dd * dd; }
  vs = warp_red_sum(vs);
  if ((t & 63) == 0) red[t >> 6] = vs;
  __syncthreads();
  if (t == 0) istd = rsqrtf((red[0] + red[1] + red[2] + red[3]) * (1.f / DNN) + 1e-5f);
  __syncthreads();
  #pragma unroll
  for (int k4 = 0; k4 < 4; ++k4) {
    int c = t + k4 * 256;
    out[(size_t)i * DNN + c] = (vals[k4] - mu) * istd * g[c] + b[c];
  }
}

extern "C" void kernel_launch(void* const* d_in, const int* in_sizes, int n_in,
                              void* d_out, int out_size, void* d_ws, size_t ws_size,
                              hipStream_t stream) {
  const float* R      = (const float*)d_in[0];
  const float* tvec   = (const float*)d_in[1];
  const float* p_CB   = (const float*)d_in[2];
  const float* x      = (const float*)d_in[3];
  const float* z      = (const float*)d_in[4];
  const float* dmat   = (const float*)d_in[5];
  const int*   mask   = (const int*)d_in[6];
  const float* Wq     = (const float*)d_in[7];
  const float* Wk     = (const float*)d_in[8];
  const float* Wv     = (const float*)d_in[9];
  const float* Wpb    = (const float*)d_in[10];
  const float* spc    = (const float*)d_in[11];
  const float* Wout   = (const float*)d_in[12];
  const float* bout   = (const float*)d_in[13];
  const float* lng    = (const float*)d_in[14];
  const float* lnb    = (const float*)d_in[15];
  const float* wq     = (const float*)d_in[16];
  const float* wk     = (const float*)d_in[17];
  const float* wv     = (const float*)d_in[18];
  const float* wlng   = (const float*)d_in[19];
  const float* wlnb   = (const float*)d_in[20];
  const float* Wa1    = (const float*)d_in[21];
  const float* ba1    = (const float*)d_in[22];
  const float* Wa2    = (const float*)d_in[23];
  const float* ba2    = (const float*)d_in[24];
  float* out = (float*)d_out;

  float* p = (float*)d_ws;
  auto alloc = [&](size_t n) { float* r = p; p += n; return r; };
  float* q_     = alloc(196608);   // 1024*192
  float* k_     = alloc(196608);
  float* v_     = alloc(196608);
  float* feat   = alloc(1069056);  // 1024*1044
  float* fgemm  = alloc(1048576);  // 1024*1024
  float* pacc   = alloc((size_t)1024 * SPLITJ * 1024);  // 16.8 MB
  float* xsum   = alloc(1024);
  float* d2row  = alloc(1024);
  float* sum_lp = alloc(1024);
  float* wpbsum = alloc(64);
  float* lamBase= alloc(16);
  float* Gsum   = alloc(4);
  float* coefs  = alloc(16);
  float* Ksum   = alloc(192);
  float* xw     = alloc(3072);
  float* qkvw   = alloc(1728);
  float* yln    = alloc(576);
  float* hid    = alloc(3072);

  hipMemsetAsync(xsum, 0, 1024 * sizeof(float), stream);

  k_gemm_qkv<<<dim3(9, 16), 256, 0, stream>>>(x, Wq, Wk, Wv, q_, k_, v_);
  k_xsum<<<64, 256, 0, stream>>>(x, xsum);
  k_misc<<<1, 64, 0, stream>>>(Wpb, spc, wpbsum, lamBase, Gsum);
  k_d2row<<<1024, 256, 0, stream>>>(dmat, d2row);
  k_sumlp<<<1024, 256, 0, stream>>>(z, wpbsum, sum_lp);
  k_ksum<<<3, 64, 0, stream>>>(xsum, Wk, Ksum);
  k_xw<<<4, 256, 0, stream>>>(q_, Ksum, sum_lp, d2row, Gsum, xw);
  k_qkvw<<<7, 256, 0, stream>>>(xw, wq, wk, wv, qkvw);
  k_tiny<<<1, 256, 0, stream>>>(qkvw, wlng, wlnb, yln);
  k_hid<<<12, 256, 0, stream>>>(yln, Wa1, ba1, hid);
  k_abc<<<1, 256, 0, stream>>>(hid, Wa2, ba2, lamBase, coefs);
  k_main<<<dim3(1024, SPLITJ), 512, 0, stream>>>(z, dmat, mask, q_, k_, v_, Wpb,
                                                 p_CB, coefs, pacc);
  k_merge<<<1024, 256, 0, stream>>>(pacc, R, tvec, feat);
  k_gemm_feat<<<dim3(16, 16), 256, 0, stream>>>(feat, Wout, fgemm);
  k_final<<<1024, 256, 0, stream>>>(x, fgemm, bout, mask, lng, lnb, out);
}